// Round 1
// baseline (149.433 us; speedup 1.0000x reference)
//
#include <hip/hip_runtime.h>

#define WD 64
#define NN 4096
#define RCAP 64     // per-row bucket capacity, CSR/CSC of Lcm (max observed ~45, Poisson(20))
#define XCAP 256    // per-row bucket capacity, LOC/IU off-diagonal extras (mean ~14)

typedef float v4f __attribute__((ext_vector_type(4)));  // native vector: nontemporal-store OK

// Buckets hold packed entries: int2{ index, float_bits(value) }

// ---- Pass 1: direct bucket scatter (CSR, CSC, extras) + Lcm row sums + dense extra-diagonal ----
__global__ void k_scatter(const int* __restrict__ wrow, const int* __restrict__ wcol,
                          const float* __restrict__ wdata, const float* __restrict__ cmw,
                          const int* __restrict__ locInd, const float* __restrict__ locFlows,
                          const float* __restrict__ locw,
                          const int* __restrict__ iuInd, const float* __restrict__ iuFlows,
                          const int* __restrict__ iuNeigh, const float* __restrict__ iuw,
                          int nnz, int mloc, int miu,
                          int* __restrict__ curR, int* __restrict__ curC, int* __restrict__ curX,
                          float* __restrict__ rowsum, float* __restrict__ diagX,
                          int2* __restrict__ sR, int2* __restrict__ sC, int2* __restrict__ xE) {
    int t = blockIdx.x * blockDim.x + threadIdx.x;
    if (t < nnz) {
        // CM entries: one thread per COO entry
        int r = wrow[t], c = wcol[t];
        float pos = wdata[t] * cmw[r];
        float v = -pos;                        // Lcm off-diagonal value
        atomicAdd(&rowsum[r], pos);
        int pR = atomicAdd(&curR[r], 1);
        if (pR < RCAP) sR[r * RCAP + pR] = make_int2(c, __float_as_int(v));
        int pC = atomicAdd(&curC[c], 1);
        if (pC < RCAP) sC[c * RCAP + pC] = make_int2(r, __float_as_int(v));
        return;
    }
    t -= nnz;
    if (t < mloc) {
        // LOC: one thread per m. Consecutive threads -> consecutive m -> flow loads
        // coalesce across the wave for each j. r = neigh[m,0] is shared by all 9 j:
        // reserve 9 slots with ONE atomic, burst-store 72 B contiguously.
        int m = t;
        int ind = locInd[m];
        float w = locw[ind];
        int r = ind - 1 - WD;                  // == ind + offs[0]
        int base = atomicAdd(&curX[r], 9);
        int   cs[9];
        float hs[9];
        float hsum = 0.f;
        #pragma unroll
        for (int j = 0; j < 9; ++j) {
            int c = ind + (j / 3 - 1) + (j % 3 - 1) * WD;   // offs[j], no scratch array
            float h = 0.5f * locFlows[j * 9 * mloc + m] * w;
            cs[j] = c; hs[j] = h; hsum += h;
            if (base + j < XCAP)
                xE[r * XCAP + base + j] = make_int2(c, __float_as_int(-h)); // A[r,c] -= h
        }
        atomicAdd(&diagX[r], hsum);            // A[r,r] += sum_j h_j
        int slots[9];
        #pragma unroll
        for (int j = 0; j < 9; ++j) slots[j] = atomicAdd(&curX[cs[j]], 1);  // independent, overlap
        #pragma unroll
        for (int j = 0; j < 9; ++j) {
            if (slots[j] < XCAP)
                xE[cs[j] * XCAP + slots[j]] = make_int2(r, __float_as_int(-hs[j])); // A[c,r] -= h
            atomicAdd(&diagX[cs[j]], hs[j]);   // A[c,c] += h
        }
        return;
    }
    t -= mloc;
    if (t < miu) {
        // IU: one thread per m; r = IU_inInd[m] shared by all 5 j.
        int m = t;
        int r = iuInd[m];
        float w = iuw[r];
        int base = atomicAdd(&curX[r], 5);
        int   cs[5];
        float hs[5];
        float hsum = 0.f;
        #pragma unroll
        for (int j = 0; j < 5; ++j) {
            int c = iuNeigh[m * 5 + j];
            float h = 0.5f * iuFlows[m * 5 + j] * w;
            cs[j] = c; hs[j] = h; hsum += h;
            if (base + j < XCAP)
                xE[r * XCAP + base + j] = make_int2(c, __float_as_int(-h));
        }
        atomicAdd(&diagX[r], hsum);
        int slots[5];
        #pragma unroll
        for (int j = 0; j < 5; ++j) slots[j] = atomicAdd(&curX[cs[j]], 1);
        #pragma unroll
        for (int j = 0; j < 5; ++j) {
            if (slots[j] < XCAP)
                xE[cs[j] * XCAP + slots[j]] = make_int2(r, __float_as_int(-hs[j]));
            atomicAdd(&diagX[cs[j]], hs[j]);
        }
    }
}

// ---- Pass 2: one block per output row; dense LDS accumulator; single streaming write ----
__global__ void __launch_bounds__(256) k_rows(
    const int* __restrict__ curR, const int2* __restrict__ sR,
    const int* __restrict__ curC, const int2* __restrict__ sC,
    const int* __restrict__ curX, const int2* __restrict__ xE,
    const float* __restrict__ rowsum, const float* __restrict__ diagX,
    const float* __restrict__ kuw, const float* __restrict__ conf, const float* __restrict__ known,
    const float* __restrict__ kToU, const float* __restrict__ lmbda,
    float* __restrict__ A, float* __restrict__ b) {
    __shared__ float acc[NN];
    __shared__ int   ck[RCAP + 1];   // CSC row index k
    __shared__ float cv[RCAP + 1];   // Lcm[k,i]
    __shared__ int   crl[RCAP + 1];  // nnz of CSR row k
    __shared__ float crs[RCAP + 1];  // rowsum[k] (synthetic diagonal of row k)
    int i = blockIdx.x;
    int tid = threadIdx.x;

    // Stage column-i metadata FIRST so its two dependent global-latency rounds
    // (sC entry -> curR/rowsum gather) overlap the 16 KB LDS zeroing below.
    int ccnt = min(curC[i], RCAP);
    int ctot = ccnt + 1;                       // + synthetic diagonal entry (i, rowsum[i])
    for (int t = tid; t < ctot; t += 256) {
        int k; float v;
        if (t < ccnt) { int2 e = sC[i * RCAP + t]; k = e.x; v = __int_as_float(e.y); }
        else          { k = i;                     v = rowsum[i]; }
        ck[t] = k; cv[t] = v;
        crl[t] = min(curR[k], RCAP);
        crs[t] = rowsum[k];
    }

    v4f* acc4 = (v4f*)acc;
    for (int t = tid; t < NN / 4; t += 256) acc4[t] = (v4f){0.f, 0.f, 0.f, 0.f};
    __syncthreads();

    // A[i,j] = sum over column-i entries (k,v) of v * Lcm[k,j]
    // two k per wave (half-wave each) for ~2x lane utilization at ~22 nnz/row
    int wave = tid >> 6, lane = tid & 63;
    int sub = lane >> 5, hl = lane & 31;
    for (int kk = wave * 2 + sub; kk < ctot; kk += 8) {
        int k = ck[kk];
        float v = cv[kk];
        int rl = crl[kk];
        const int2* rowp = sR + k * RCAP;
        for (int t = hl; t <= rl; t += 32) {   // rl entries + synthetic diag (k, rowsum[k])
            int j; float w;
            if (t < rl) { int2 e = rowp[t]; j = e.x; w = __int_as_float(e.y); }
            else        { j = k; w = crs[kk]; }
            atomicAdd(&acc[j], v * w);
        }
    }
    // LOC/IU grouped off-diagonal contributions for this row
    int xc = min(curX[i], XCAP);
    const int2* xp = xE + i * XCAP;
    for (int t = tid; t < xc; t += 256) {
        int2 e = xp[t];
        atomicAdd(&acc[e.x], __int_as_float(e.y));
    }
    // diagonal: regularizer + accumulated LOC/IU diagonal; b
    if (tid == 0) {
        float d = kuw[i] * conf[i] + lmbda[0] * known[i];
        b[i] = d * kToU[i];
        atomicAdd(&acc[i], d + diagX[i]);
    }
    __syncthreads();

    v4f* out4 = (v4f*)(A + (size_t)i * NN);
    for (int t = tid; t < NN / 4; t += 256)
        __builtin_nontemporal_store(acc4[t], &out4[t]);  // A > L2 capacity; don't pollute
}

extern "C" void kernel_launch(void* const* d_in, const int* in_sizes, int n_in,
                              void* d_out, int out_size, void* d_ws, size_t ws_size,
                              hipStream_t stream) {
    const float* CM_weights  = (const float*)d_in[2];
    const float* LOC_weights = (const float*)d_in[3];
    const float* IU_weights  = (const float*)d_in[4];
    const float* KU_weights  = (const float*)d_in[5];
    const float* lmbda       = (const float*)d_in[6];
    const float* kToUconf    = (const float*)d_in[7];
    const float* known       = (const float*)d_in[8];
    const float* kToU        = (const float*)d_in[9];
    const int*   Wcm_row     = (const int*)d_in[10];
    const int*   Wcm_col     = (const int*)d_in[11];
    const float* Wcm_data    = (const float*)d_in[12];
    const int*   LOC_inInd   = (const int*)d_in[13];
    const float* LOC_flows   = (const float*)d_in[14];
    const int*   IU_inInd    = (const int*)d_in[15];
    const float* IU_flows    = (const float*)d_in[16];
    const int*   IU_neighInd = (const int*)d_in[17];

    int nnz  = in_sizes[10];
    int mloc = in_sizes[13];
    int miu  = in_sizes[15];

    float* A = (float*)d_out;
    float* b = A + (size_t)NN * NN;

    // workspace layout (4B words):
    // [curR|curC|curX|rowsum|diagX] (zeroed, 5*NN) |
    // sR (NN*RCAP int2, 2MB) | sC (NN*RCAP int2, 2MB) | xE (NN*XCAP int2, 8MB)
    int*   curR   = (int*)d_ws;
    int*   curC   = curR + NN;
    int*   curX   = curC + NN;
    float* rowsum = (float*)(curX + NN);
    float* diagX  = rowsum + NN;
    int2*  sR     = (int2*)(diagX + NN);
    int2*  sC     = sR + (size_t)NN * RCAP;
    int2*  xE     = sC + (size_t)NN * RCAP;

    (void)hipMemsetAsync(curR, 0, 5 * NN * sizeof(int), stream);  // curR,curC,curX,rowsum,diagX

    int tt = nnz + mloc + miu;
    int blks = (tt + 255) / 256;
    k_scatter<<<blks, 256, 0, stream>>>(Wcm_row, Wcm_col, Wcm_data, CM_weights,
                                        LOC_inInd, LOC_flows, LOC_weights,
                                        IU_inInd, IU_flows, IU_neighInd, IU_weights,
                                        nnz, mloc, miu, curR, curC, curX, rowsum, diagX,
                                        sR, sC, xE);
    k_rows<<<NN, 256, 0, stream>>>(curR, sR, curC, sC, curX, xE, rowsum, diagX,
                                   KU_weights, kToUconf, known, kToU, lmbda, A, b);
}

// Round 2
// 138.106 us; speedup vs baseline: 1.0820x; 1.0820x over previous
//
#include <hip/hip_runtime.h>

#define WD 64
#define NN 4096
#define RCAP 64     // per-row bucket capacity, CSR/CSC of Lcm (max observed ~45, Poisson(20))
#define XCAP 256    // per-row bucket capacity, LOC/IU extras incl. diagonal (mean ~28)

typedef float v4f __attribute__((ext_vector_type(4)));  // native vector: nontemporal-store OK

// Buckets hold packed entries: int2{ index, float_bits(value) }

// ---- Pass 1: direct bucket scatter (CSR, CSC, extras) + Lcm row sums ----
__global__ void k_scatter(const int* __restrict__ wrow, const int* __restrict__ wcol,
                          const float* __restrict__ wdata, const float* __restrict__ cmw,
                          const int* __restrict__ locInd, const float* __restrict__ locFlows,
                          const float* __restrict__ locw,
                          const int* __restrict__ iuInd, const float* __restrict__ iuFlows,
                          const int* __restrict__ iuNeigh, const float* __restrict__ iuw,
                          int nnz, int mloc, int miu,
                          int* __restrict__ curR, int* __restrict__ curC, int* __restrict__ curX,
                          float* __restrict__ rowsum,
                          int2* __restrict__ sR, int2* __restrict__ sC, int2* __restrict__ xE) {
    int t = blockIdx.x * blockDim.x + threadIdx.x;
    if (t < nnz) {
        // CM entries: one thread per COO entry
        int r = wrow[t], c = wcol[t];
        float pos = wdata[t] * cmw[r];
        float v = -pos;                        // Lcm off-diagonal value
        atomicAdd(&rowsum[r], pos);
        int pR = atomicAdd(&curR[r], 1);
        if (pR < RCAP) sR[r * RCAP + pR] = make_int2(c, __float_as_int(v));
        int pC = atomicAdd(&curC[c], 1);
        if (pC < RCAP) sC[c * RCAP + pC] = make_int2(r, __float_as_int(v));
        return;
    }
    t -= nnz;
    if (t < mloc * 9) {
        // LOC: one thread per (m, j), m-FASTEST mapping: consecutive lanes share j and
        // read consecutive locFlows[j*9*mloc + m] -> coalesced (j-fastest strided 72KB).
        // j is wave-uniform -> offset math scalarizes.
        int j = t / mloc;
        int m = t - j * mloc;
        int ind = locInd[m];
        int r = ind - 1 - WD;                  // neigh[m,0]
        int c = ind + (j / 3 - 1) + (j % 3 - 1) * WD;   // offs[j]
        float h = 0.5f * locFlows[j * 9 * mloc + m] * locw[ind];
        // every curX reservation is +2 -> offsets always even -> int4 (16B) aligned
        int p1 = atomicAdd(&curX[r], 2);
        if (p1 + 1 < XCAP)                      // A[r,c] -= h ; A[r,r] += h
            *(int4*)&xE[r * XCAP + p1] = make_int4(c, __float_as_int(-h), r, __float_as_int(h));
        int p2 = atomicAdd(&curX[c], 2);
        if (p2 + 1 < XCAP)                      // A[c,r] -= h ; A[c,c] += h
            *(int4*)&xE[c * XCAP + p2] = make_int4(r, __float_as_int(-h), c, __float_as_int(h));
        return;
    }
    t -= mloc * 9;
    if (t < miu * 5) {
        // IU: j-fastest (flows/neighInd already contiguous across the wave this way)
        int m = t / 5;
        int j = t - m * 5;
        int r = iuInd[m];
        int c = iuNeigh[m * 5 + j];
        float h = 0.5f * iuFlows[m * 5 + j] * iuw[r];
        int p1 = atomicAdd(&curX[r], 2);
        if (p1 + 1 < XCAP)
            *(int4*)&xE[r * XCAP + p1] = make_int4(c, __float_as_int(-h), r, __float_as_int(h));
        int p2 = atomicAdd(&curX[c], 2);
        if (p2 + 1 < XCAP)
            *(int4*)&xE[c * XCAP + p2] = make_int4(r, __float_as_int(-h), c, __float_as_int(h));
    }
}

// ---- Pass 2: one block per output row; dense LDS accumulator; single streaming write ----
__global__ void __launch_bounds__(256) k_rows(
    const int* __restrict__ curR, const int2* __restrict__ sR,
    const int* __restrict__ curC, const int2* __restrict__ sC,
    const int* __restrict__ curX, const int2* __restrict__ xE,
    const float* __restrict__ rowsum,
    const float* __restrict__ kuw, const float* __restrict__ conf, const float* __restrict__ known,
    const float* __restrict__ kToU, const float* __restrict__ lmbda,
    float* __restrict__ A, float* __restrict__ b) {
    __shared__ float acc[NN];
    __shared__ int   ck[RCAP + 1];   // CSC row index k
    __shared__ float cv[RCAP + 1];   // Lcm[k,i]
    __shared__ int   crl[RCAP + 1];  // nnz of CSR row k
    __shared__ float crs[RCAP + 1];  // rowsum[k] (synthetic diagonal of row k)
    int i = blockIdx.x;
    int tid = threadIdx.x;

    // Stage column-i metadata FIRST so its two dependent global-latency rounds
    // (sC entry -> curR/rowsum gather) overlap the 16 KB LDS zeroing below.
    int ccnt = min(curC[i], RCAP);
    int ctot = ccnt + 1;                       // + synthetic diagonal entry (i, rowsum[i])
    for (int t = tid; t < ctot; t += 256) {
        int k; float v;
        if (t < ccnt) { int2 e = sC[i * RCAP + t]; k = e.x; v = __int_as_float(e.y); }
        else          { k = i;                     v = rowsum[i]; }
        ck[t] = k; cv[t] = v;
        crl[t] = min(curR[k], RCAP);
        crs[t] = rowsum[k];
    }

    v4f* acc4 = (v4f*)acc;
    for (int t = tid; t < NN / 4; t += 256) acc4[t] = (v4f){0.f, 0.f, 0.f, 0.f};
    __syncthreads();

    // A[i,j] = sum over column-i entries (k,v) of v * Lcm[k,j]
    // two k per wave (half-wave each) for ~2x lane utilization at ~22 nnz/row
    int wave = tid >> 6, lane = tid & 63;
    int sub = lane >> 5, hl = lane & 31;
    for (int kk = wave * 2 + sub; kk < ctot; kk += 8) {
        int k = ck[kk];
        float v = cv[kk];
        int rl = crl[kk];
        const int2* rowp = sR + k * RCAP;
        for (int t = hl; t <= rl; t += 32) {   // rl entries + synthetic diag (k, rowsum[k])
            int j; float w;
            if (t < rl) { int2 e = rowp[t]; j = e.x; w = __int_as_float(e.y); }
            else        { j = k; w = crs[kk]; }
            atomicAdd(&acc[j], v * w);
        }
    }
    // LOC/IU grouped contributions for this row (off-diagonal + diagonal packed pairs)
    int xc = min(curX[i], XCAP);
    const int2* xp = xE + i * XCAP;
    for (int t = tid; t < xc; t += 256) {
        int2 e = xp[t];
        atomicAdd(&acc[e.x], __int_as_float(e.y));
    }
    // diagonal regularizer + b
    if (tid == 0) {
        float d = kuw[i] * conf[i] + lmbda[0] * known[i];
        atomicAdd(&acc[i], d);
        b[i] = d * kToU[i];
    }
    __syncthreads();

    v4f* out4 = (v4f*)(A + (size_t)i * NN);
    for (int t = tid; t < NN / 4; t += 256)
        __builtin_nontemporal_store(acc4[t], &out4[t]);  // A > L2 capacity; don't pollute
}

extern "C" void kernel_launch(void* const* d_in, const int* in_sizes, int n_in,
                              void* d_out, int out_size, void* d_ws, size_t ws_size,
                              hipStream_t stream) {
    const float* CM_weights  = (const float*)d_in[2];
    const float* LOC_weights = (const float*)d_in[3];
    const float* IU_weights  = (const float*)d_in[4];
    const float* KU_weights  = (const float*)d_in[5];
    const float* lmbda       = (const float*)d_in[6];
    const float* kToUconf    = (const float*)d_in[7];
    const float* known       = (const float*)d_in[8];
    const float* kToU        = (const float*)d_in[9];
    const int*   Wcm_row     = (const int*)d_in[10];
    const int*   Wcm_col     = (const int*)d_in[11];
    const float* Wcm_data    = (const float*)d_in[12];
    const int*   LOC_inInd   = (const int*)d_in[13];
    const float* LOC_flows   = (const float*)d_in[14];
    const int*   IU_inInd    = (const int*)d_in[15];
    const float* IU_flows    = (const float*)d_in[16];
    const int*   IU_neighInd = (const int*)d_in[17];

    int nnz  = in_sizes[10];
    int mloc = in_sizes[13];
    int miu  = in_sizes[15];

    float* A = (float*)d_out;
    float* b = A + (size_t)NN * NN;

    // workspace layout (4B words):
    // [curR|curC|curX|rowsum] (zeroed, 4*NN) |
    // sR (NN*RCAP int2, 2MB) | sC (NN*RCAP int2, 2MB) | xE (NN*XCAP int2, 8MB)
    int*   curR   = (int*)d_ws;
    int*   curC   = curR + NN;
    int*   curX   = curC + NN;
    float* rowsum = (float*)(curX + NN);
    int2*  sR     = (int2*)(rowsum + NN);
    int2*  sC     = sR + (size_t)NN * RCAP;
    int2*  xE     = sC + (size_t)NN * RCAP;

    (void)hipMemsetAsync(curR, 0, 4 * NN * sizeof(int), stream);  // curR,curC,curX,rowsum

    int tt = nnz + mloc * 9 + miu * 5;
    int blks = (tt + 255) / 256;
    k_scatter<<<blks, 256, 0, stream>>>(Wcm_row, Wcm_col, Wcm_data, CM_weights,
                                        LOC_inInd, LOC_flows, LOC_weights,
                                        IU_inInd, IU_flows, IU_neighInd, IU_weights,
                                        nnz, mloc, miu, curR, curC, curX, rowsum,
                                        sR, sC, xE);
    k_rows<<<NN, 256, 0, stream>>>(curR, sR, curC, sC, curX, xE, rowsum,
                                   KU_weights, kToUconf, known, kToU, lmbda, A, b);
}